// Round 4
// baseline (287.629 us; speedup 1.0000x reference)
//
#include <hip/hip_runtime.h>
#include <hip/hip_bf16.h>
#include <hip/hip_fp16.h>

// B=2048, D=256, K=256, NC=64, F=512.
// Q[b,c] = Qlin[b,c] + z^T M_c z, M_c = sum_k cq[c,k] Gamma_k.
// R4 (= R3 + compile fix): f16 spine. mc is an MFMA GEMM (HBM-bound, 72 MB);
// qf uses packed-f16 A-build (4 v_pk_mul_f16 per 2 MFMAs) + global_load_lds
// staging of a pre-swizzled mh layout; prep stages cq in LDS for coalescing.

#define B_SZ 2048
#define D_SZ 256
#define K_SZ 256
#define NC_SZ 64
#define F_SZ 512
#define P_SZ 65536

typedef float  floatx4  __attribute__((ext_vector_type(4)));
typedef float  floatx16 __attribute__((ext_vector_type(16)));
typedef _Float16 h8 __attribute__((ext_vector_type(8)));
typedef __fp16  fp16x2 __attribute__((ext_vector_type(2)));
union H8U4 { uint4 u; h8 h; };

// ws layout (f32 offsets). cqh ALIASES Q2 (dead after mc; memset follows mc).
#define WS_WZT   0        // 256*64
#define WS_WFT   16384    // 512*64
#define WS_BEFF  49152    // 64
#define WS_CSQ   49216    // 64
#define WS_CQT   49280    // 256*64  cqT[i*64+c] = cq[c*256+i]
#define WS_Q2    65664    // 2048*64 f32 (also cqh f16[64*256] during prep/mc)
#define WS_MH    196736   // f16[64*65536], XOR-swizzled within i-segments

__device__ __forceinline__ unsigned pkrtz_u(float a, float b) {
    fp16x2 r = __builtin_amdgcn_cvt_pkrtz(a, b);
    return __builtin_bit_cast(unsigned, r);
}

__device__ __forceinline__ void gload16(const void* g, void* l) {
    __builtin_amdgcn_global_load_lds(
        (const __attribute__((address_space(1))) unsigned*)g,
        (__attribute__((address_space(3))) unsigned*)l, 16, 0, 0);
}

// ---------------- prep: collapsed weights, cqT, cqh, beff, csq --------------
// blocks 0..63: WZT (4 i each) | 64..191: WFT (4 j each) | 192: beff/csq
// 193..200: cqh f16 convert. cq staged in LDS (pitch 257 -> 2-way, free).
__global__ __launch_bounds__(256) void prep_kernel(
        const float* __restrict__ Wqz, const float* __restrict__ bqz,
        const float* __restrict__ Wqf, const float* __restrict__ bqf,
        const float* __restrict__ cq,  float* __restrict__ ws) {
    const int tid = threadIdx.x;
    const int w = tid >> 6, c = tid & 63;
    const int bid = blockIdx.x;

    if (bid >= 193) {  // cqh convert: no barrier on this path
        _Float16* cqh = (_Float16*)(ws + WS_Q2);
        const int idx = (bid - 193)*256 + tid;   // 0..2047, 8 f16 each
        const floatx4* sp = (const floatx4*)(cq + idx*8);
        floatx4 a = sp[0], b = sp[1];
        uint4 u = { pkrtz_u(a[0],a[1]), pkrtz_u(a[2],a[3]),
                    pkrtz_u(b[0],b[1]), pkrtz_u(b[2],b[3]) };
        *(uint4*)(cqh + idx*8) = u;
        return;
    }

    __shared__ float cqL[64*257];
    #pragma unroll
    for (int s = 0; s < 16; ++s) {
        const int e4 = s*256 + tid;             // float4 index over cq
        const int row = e4 >> 6, col = (e4 & 63)*4;
        floatx4 v = *(const floatx4*)(cq + e4*4);
        #pragma unroll
        for (int u = 0; u < 4; ++u) cqL[row*257 + col + u] = v[u];
    }
    __syncthreads();

    if (bid < 64) {
        const int i = bid*4 + w;
        float acc = 0.f;
        #pragma unroll 4
        for (int k = 0; k < K_SZ; ++k)
            acc = fmaf(cqL[c*257 + k], Wqz[k*D_SZ + i], acc);
        ws[WS_WZT + i*64 + c] = acc;
        ws[WS_CQT + i*64 + c] = cqL[c*257 + i];
    } else if (bid < 192) {
        const int j = (bid - 64)*4 + w;
        float acc = 0.f;
        #pragma unroll 4
        for (int k = 0; k < K_SZ; ++k)
            acc = fmaf(cqL[c*257 + k], Wqf[k*F_SZ + j], acc);
        ws[WS_WFT + j*64 + c] = acc;
    } else {
        if (w == 0) {
            float acc = 0.f;
            for (int k = 0; k < K_SZ; ++k)
                acc = fmaf(cqL[c*257 + k], bqz[k] + bqf[k], acc);
            ws[WS_BEFF + c] = acc;
        } else if (w == 1) {
            float acc = 0.f;
            for (int i = 0; i < D_SZ; ++i) {
                const float v = cqL[c*257 + i];
                acc = fmaf(v, v, acc);
            }
            ws[WS_CSQ + c] = acc;
        }
    }
}

// ---------------- mc: M[c,p] = sum_k cq[c,k] Gamma[k,p] via MFMA ------------
// grid 1024: p-tile 64/block. HBM-bound (64 MB Gamma read once + 8 MB write).
// Wave (mt,ns): mt = c-half, ns = p-half. Output stored f16, XOR-swizzled.
__global__ __launch_bounds__(256, 4) void mc_kernel(
        const float* __restrict__ gamma, const _Float16* __restrict__ cqh,
        _Float16* __restrict__ mh) {
    __shared__ __align__(16) float gl[32*64];   // Gamma chunk [k=32][p=64] f32
    const int tid = threadIdx.x;
    const int w = tid >> 6, lane = tid & 63;
    const int ln = lane & 31, half = lane >> 5;
    const int mt = w >> 1, ns = w & 1;
    const int p0 = blockIdx.x * 64;
    const int iseg = p0 >> 8, j0 = p0 & 255;

    floatx16 acc;
    #pragma unroll
    for (int r = 0; r < 16; ++r) acc[r] = 0.f;

    const int arow = mt*32 + ln;
    for (int kc = 0; kc < 8; ++kc) {
        #pragma unroll
        for (int s = 0; s < 2; ++s) {
            const int e = s*256 + tid;
            const int row = e >> 4, c4 = e & 15;
            gload16(gamma + (size_t)(kc*32 + row)*P_SZ + p0 + c4*4,
                    (char*)gl + e*16);
        }
        __syncthreads();   // compiler drains vmcnt before s_barrier
        #pragma unroll
        for (int ks = 0; ks < 2; ++ks) {
            H8U4 a; a.u = *(const uint4*)(cqh + arow*256 + kc*32 + ks*16 + half*8);
            const float* gp = gl + (ks*16 + half*8)*64 + ns*32 + ln;
            H8U4 b;
            b.u.x = pkrtz_u(gp[0],   gp[64]);
            b.u.y = pkrtz_u(gp[128], gp[192]);
            b.u.z = pkrtz_u(gp[256], gp[320]);
            b.u.w = pkrtz_u(gp[384], gp[448]);
            acc = __builtin_amdgcn_mfma_f32_32x32x16_f16(a.h, b.h, acc, 0, 0, 0);
        }
        __syncthreads();
    }
    // D: col=lane&31 (p), row=(r&3)+8*(r>>2)+4*half (c)  [m74/m101]
    #pragma unroll
    for (int r = 0; r < 16; ++r) {
        const int cc = mt*32 + (r&3) + 8*(r>>2) + 4*half;
        const int j  = j0 + ns*32 + ln;
        const int jc = j >> 3, off = j & 7;
        mh[(size_t)cc*P_SZ + iseg*256 + ((jc ^ (cc&31))*8 + off)] = (_Float16)acc[r];
    }
}

// ---------------- lin: qlin atomic GEMM (2 b-rows/wave) ---------------------
__global__ __launch_bounds__(256) void lin_kernel(
        const float* __restrict__ z, const float* __restrict__ feat,
        const float* __restrict__ ws, float* __restrict__ q2) {
    const int w = threadIdx.x >> 6, c = threadIdx.x & 63;
    const int half = blockIdx.x & 1, bp = blockIdx.x >> 1;
    const int b0 = bp*8 + w*2;
    const float* __restrict__ wzT = ws + WS_WZT + half*128*64;
    const float* __restrict__ wfT = ws + WS_WFT + half*256*64;
    const float* __restrict__ z0 = z + b0*D_SZ + half*128;
    const float* __restrict__ z1 = z0 + D_SZ;
    float q0 = 0.f, q1 = 0.f;
    #pragma unroll 4
    for (int i = 0; i < 128; ++i) {
        const float wv = wzT[i*64 + c];
        q0 = fmaf(z0[i], wv, q0);
        q1 = fmaf(z1[i], wv, q1);
    }
    const float* __restrict__ f0 = feat + b0*F_SZ + half*256;
    const float* __restrict__ f1 = f0 + F_SZ;
    #pragma unroll 4
    for (int j = 0; j < 256; ++j) {
        const float wv = wfT[j*64 + c];
        q0 = fmaf(f0[j], wv, q0);
        q1 = fmaf(f1[j], wv, q1);
    }
    atomicAdd(q2 + b0*64 + c, q0);
    atomicAdd(q2 + (b0 + 1)*64 + c, q1);
}

// ---------------- qf: Q2 += zz^T : M via mfma_f32_32x32x16_f16 --------------
// grid (16, 64): b-tile 128, i-group 4. A built with v_pk_mul_f16 from
// preloaded f16 zj; B staged via global_load_lds (mh pre-swizzled).
__global__ __launch_bounds__(256, 4) void qf_kernel(
        const float* __restrict__ z, const _Float16* __restrict__ mh,
        float* __restrict__ q2) {
    __shared__ __align__(16) char bt[64 * 512];
    const int tid = threadIdx.x;
    const int w = tid >> 6, lane = tid & 63;
    const int ln = lane & 31, half = lane >> 5;
    const int b0 = blockIdx.x * 128;
    const int ig = blockIdx.y;              // i-group of 4
    const int bb = b0 + w*32 + ln;          // A-operand m-row

    // zjh[ch] = f16(z[bb][ch*16 + half*8 .. +7]) packed, 64 VGPRs
    uint4 zjh[16];
    #pragma unroll
    for (int ch = 0; ch < 16; ++ch) {
        const floatx4* zp = (const floatx4*)(z + bb*D_SZ + ch*16 + half*8);
        floatx4 a = zp[0], b = zp[1];
        zjh[ch].x = pkrtz_u(a[0], a[1]);
        zjh[ch].y = pkrtz_u(a[2], a[3]);
        zjh[ch].z = pkrtz_u(b[0], b[1]);
        zjh[ch].w = pkrtz_u(b[2], b[3]);
    }
    const floatx4 ziv = *(const floatx4*)(z + bb*D_SZ + ig*4);

    floatx16 acc0, acc1;
    #pragma unroll
    for (int r = 0; r < 16; ++r) { acc0[r] = 0.f; acc1[r] = 0.f; }

    for (int il = 0; il < 4; ++il) {
        const int i = ig*4 + il;
        #pragma unroll
        for (int s = 0; s < 8; ++s) {       // 32 KB: [c=64][256 f16] (physical)
            const int e = s*256 + tid;
            gload16((const char*)mh + ((size_t)(e >> 5)*P_SZ + (size_t)i*256)*2 + (e & 31)*16,
                    bt + e*16);
        }
        __syncthreads();

        const float zi = ziv[il];
        const unsigned zu = pkrtz_u(zi, zi);
        H8U4 zb; zb.u.x = zu; zb.u.y = zu; zb.u.z = zu; zb.u.w = zu;
        #pragma unroll
        for (int ch = 0; ch < 16; ++ch) {
            H8U4 aj; aj.u = zjh[ch];
            h8 af = aj.h * zb.h;            // 4x v_pk_mul_f16
            const int pc = ((ch*2 + half) ^ ln) * 16;   // de-swizzle
            H8U4 f0, f1;
            f0.u = *(const uint4*)(bt + ln*512 + pc);
            f1.u = *(const uint4*)(bt + (32 + ln)*512 + pc);
            acc0 = __builtin_amdgcn_mfma_f32_32x32x16_f16(af, f0.h, acc0, 0, 0, 0);
            acc1 = __builtin_amdgcn_mfma_f32_32x32x16_f16(af, f1.h, acc1, 0, 0, 0);
        }
        __syncthreads();
    }

    // C/D: col=lane&31 (c), row=(r&3)+8*(r>>2)+4*half (b)  [m74/m101]
    #pragma unroll
    for (int r = 0; r < 16; ++r) {
        const int row  = (r&3) + 8*(r>>2) + 4*half;
        const int brow = b0 + w*32 + row;
        atomicAdd(q2 + brow*NC_SZ + ln,      acc0[r]);
        atomicAdd(q2 + brow*NC_SZ + 32 + ln, acc1[r]);
    }
}

// ---------------- final: dot/r2 + f64 score + softmax/argmax ----------------
__global__ __launch_bounds__(256) void final_kernel(
        const float* __restrict__ z, const float* __restrict__ ws,
        float* __restrict__ out) {
    const int w = threadIdx.x >> 6, c = threadIdx.x & 63;
    const int b = blockIdx.x*4 + w;
    const float* __restrict__ zr  = z + b*D_SZ;
    const float* __restrict__ cqT = ws + WS_CQT;

    float dot = 0.f, r2 = 0.f;
    #pragma unroll 4
    for (int i = 0; i < D_SZ; ++i) {
        const float zi = zr[i];                 // wave-uniform -> scalar
        dot = fmaf(zi, cqT[i*64 + c], dot);     // coalesced
        r2  = fmaf(zi, zi, r2);
    }
    const float Q   = ws[WS_Q2 + b*64 + c] + ws[WS_BEFF + c];
    const float csq = ws[WS_CSQ + c];
    const float dsq = fmaf(-2.f, dot, r2) + csq;

    const double r2d = (double)r2, csqd = (double)csq, dsqd = (double)dsq;
    const double denom = (1.0 - r2d) * (1.0 - csqd);
    double arg = 1.0 + 2.0 * dsqd / (denom + 0.001);
    if (arg < 1.001) arg = 1.001;
    const double dist = acosh(arg);
    double tmp = 1.0 - r2d; if (tmp < 0.001) tmp = 0.001;
    double tau = 8.0 * tmp;  // sqrt(256)*0.5
    if (tau < 0.01) tau = 0.01;
    double r2c = r2d; if (r2c > 0.999) r2c = 0.999;
    const double lam = 2.0 / (1.0 - r2c + 0.001);
    const double score = -dist / tau + 0.1 * ((double)Q / lam) / tau;

    double m = score;
    #pragma unroll
    for (int off = 32; off > 0; off >>= 1) {
        double o = __shfl_xor(m, off, 64);
        m = fmax(m, o);
    }
    const double e = exp(score - m);
    double s = e;
    #pragma unroll
    for (int off = 32; off > 0; off >>= 1) s += __shfl_xor(s, off, 64);
    out[b*NC_SZ + c] = (float)(e / s);

    double bsc = score; int bix = c;
    #pragma unroll
    for (int off = 32; off > 0; off >>= 1) {
        double osc = __shfl_xor(bsc, off, 64);
        int    oix = __shfl_xor(bix, off, 64);
        if (osc > bsc || (osc == bsc && oix < bix)) { bsc = osc; bix = oix; }
    }
    if (c == 0) out[B_SZ*NC_SZ + b] = (float)bix;
}

extern "C" void kernel_launch(void* const* d_in, const int* in_sizes, int n_in,
                              void* d_out, int out_size, void* d_ws, size_t ws_size,
                              hipStream_t stream) {
    const float* z    = (const float*)d_in[0];
    const float* feat = (const float*)d_in[1];
    const float* Wqz  = (const float*)d_in[2];
    const float* bqz  = (const float*)d_in[3];
    const float* Wqf  = (const float*)d_in[4];
    const float* bqf  = (const float*)d_in[5];
    const float* gamma= (const float*)d_in[6];
    const float* cq   = (const float*)d_in[7];
    float* out = (float*)d_out;
    float* ws  = (float*)d_ws;
    _Float16* cqh = (_Float16*)(ws + WS_Q2);   // alias: dead after mc
    _Float16* mh  = (_Float16*)(ws + WS_MH);

    prep_kernel<<<201, 256, 0, stream>>>(Wqz, bqz, Wqf, bqf, cq, ws);
    mc_kernel<<<1024, 256, 0, stream>>>(gamma, cqh, mh);
    (void)hipMemsetAsync(ws + WS_Q2, 0, (size_t)B_SZ*NC_SZ*sizeof(float), stream);
    lin_kernel<<<512, 256, 0, stream>>>(z, feat, ws, ws + WS_Q2);
    qf_kernel<<<dim3(16, 64), 256, 0, stream>>>(z, mh, ws + WS_Q2);
    final_kernel<<<512, 256, 0, stream>>>(z, ws, out);
}

// Round 5
// 261.665 us; speedup vs baseline: 1.0992x; 1.0992x over previous
//
#include <hip/hip_runtime.h>
#include <hip/hip_bf16.h>
#include <hip/hip_fp16.h>

// B=2048, D=256, K=256, NC=64, F=512.
// Q[b,c] = Qlin[b,c] + z^T M_c z, M_c = sum_k cq[c,k] Gamma_k.
// R5: qf btile=256 + LDS double-buffer + i-split 32 (halves mh re-read and
// atomic count vs R4); mc LDS-free direct-VGPR MFMA streaming GEMM; lin
// merged into final.

#define B_SZ 2048
#define D_SZ 256
#define K_SZ 256
#define NC_SZ 64
#define F_SZ 512
#define P_SZ 65536

typedef float  floatx4  __attribute__((ext_vector_type(4)));
typedef float  floatx16 __attribute__((ext_vector_type(16)));
typedef _Float16 h8 __attribute__((ext_vector_type(8)));
typedef __fp16  fp16x2 __attribute__((ext_vector_type(2)));
union H8U4 { uint4 u; h8 h; };

// ws layout (f32 offsets). cqh ALIASES Q2 (dead after mc; memset follows mc).
#define WS_WZT   0        // 256*64
#define WS_WFT   16384    // 512*64
#define WS_BEFF  49152    // 64
#define WS_CSQ   49216    // 64
#define WS_CQT   49280    // 256*64  cqT[i*64+c] = cq[c*256+i]
#define WS_Q2    65664    // 2048*64 f32 (also cqh f16[64*256] during prep/mc)
#define WS_MH    196736   // f16[64*65536], XOR-swizzled within i-segments

__device__ __forceinline__ unsigned pkrtz_u(float a, float b) {
    fp16x2 r = __builtin_amdgcn_cvt_pkrtz(a, b);
    return __builtin_bit_cast(unsigned, r);
}

__device__ __forceinline__ void gload16(const void* g, void* l) {
    __builtin_amdgcn_global_load_lds(
        (const __attribute__((address_space(1))) unsigned*)g,
        (__attribute__((address_space(3))) unsigned*)l, 16, 0, 0);
}

// ---------------- prep: collapsed weights, cqT, cqh, beff, csq --------------
__global__ __launch_bounds__(256) void prep_kernel(
        const float* __restrict__ Wqz, const float* __restrict__ bqz,
        const float* __restrict__ Wqf, const float* __restrict__ bqf,
        const float* __restrict__ cq,  float* __restrict__ ws) {
    const int tid = threadIdx.x;
    const int w = tid >> 6, c = tid & 63;
    const int bid = blockIdx.x;

    if (bid >= 193) {  // cqh convert: no barrier on this path
        _Float16* cqh = (_Float16*)(ws + WS_Q2);
        const int idx = (bid - 193)*256 + tid;   // 0..2047, 8 f16 each
        const floatx4* sp = (const floatx4*)(cq + idx*8);
        floatx4 a = sp[0], b = sp[1];
        uint4 u = { pkrtz_u(a[0],a[1]), pkrtz_u(a[2],a[3]),
                    pkrtz_u(b[0],b[1]), pkrtz_u(b[2],b[3]) };
        *(uint4*)(cqh + idx*8) = u;
        return;
    }

    __shared__ float cqL[64*257];
    #pragma unroll
    for (int s = 0; s < 16; ++s) {
        const int e4 = s*256 + tid;
        const int row = e4 >> 6, col = (e4 & 63)*4;
        floatx4 v = *(const floatx4*)(cq + e4*4);
        #pragma unroll
        for (int u = 0; u < 4; ++u) cqL[row*257 + col + u] = v[u];
    }
    __syncthreads();

    if (bid < 64) {
        const int i = bid*4 + w;
        float acc = 0.f;
        #pragma unroll 4
        for (int k = 0; k < K_SZ; ++k)
            acc = fmaf(cqL[c*257 + k], Wqz[k*D_SZ + i], acc);
        ws[WS_WZT + i*64 + c] = acc;
        ws[WS_CQT + i*64 + c] = cqL[c*257 + i];
    } else if (bid < 192) {
        const int j = (bid - 64)*4 + w;
        float acc = 0.f;
        #pragma unroll 4
        for (int k = 0; k < K_SZ; ++k)
            acc = fmaf(cqL[c*257 + k], Wqf[k*F_SZ + j], acc);
        ws[WS_WFT + j*64 + c] = acc;
    } else {
        if (w == 0) {
            float acc = 0.f;
            for (int k = 0; k < K_SZ; ++k)
                acc = fmaf(cqL[c*257 + k], bqz[k] + bqf[k], acc);
            ws[WS_BEFF + c] = acc;
        } else if (w == 1) {
            float acc = 0.f;
            for (int i = 0; i < D_SZ; ++i) {
                const float v = cqL[c*257 + i];
                acc = fmaf(v, v, acc);
            }
            ws[WS_CSQ + c] = acc;
        }
    }
}

// ---------------- mc: M[c,p] = sum_k cq[c,k] Gamma[k,p] via MFMA, no LDS ----
// grid 1024: p-tile 64/block, 4 blocks/CU, no barriers. B-fragments built
// from 8 coalesced global_load_dword of Gamma per MFMA; A from L2-hot cqh.
__global__ __launch_bounds__(256, 4) void mc_kernel(
        const float* __restrict__ gamma, const _Float16* __restrict__ cqh,
        _Float16* __restrict__ mh) {
    const int tid = threadIdx.x;
    const int w = tid >> 6, lane = tid & 63;
    const int ln = lane & 31, half = lane >> 5;
    const int mt = w >> 1, ns = w & 1;
    const int p0 = blockIdx.x * 64;
    const int iseg = p0 >> 8, j0 = p0 & 255;

    floatx16 acc;
    #pragma unroll
    for (int r = 0; r < 16; ++r) acc[r] = 0.f;

    const int arow = mt*32 + ln;
    const float* __restrict__ gbase = gamma + (size_t)(half*8)*P_SZ + p0 + ns*32 + ln;

    #pragma unroll 2
    for (int kc = 0; kc < 16; ++kc) {
        float g[8];
        #pragma unroll
        for (int kk = 0; kk < 8; ++kk)
            g[kk] = gbase[(size_t)(kc*16 + kk)*P_SZ];     // coalesced 128B/row
        H8U4 a; a.u = *(const uint4*)(cqh + arow*256 + kc*16 + half*8);
        H8U4 b;
        b.u.x = pkrtz_u(g[0], g[1]);
        b.u.y = pkrtz_u(g[2], g[3]);
        b.u.z = pkrtz_u(g[4], g[5]);
        b.u.w = pkrtz_u(g[6], g[7]);
        acc = __builtin_amdgcn_mfma_f32_32x32x16_f16(a.h, b.h, acc, 0, 0, 0);
    }
    // D: col=lane&31 (p), row=(r&3)+8*(r>>2)+4*half (c)  [m74/m101]
    #pragma unroll
    for (int r = 0; r < 16; ++r) {
        const int cc = mt*32 + (r&3) + 8*(r>>2) + 4*half;
        const int j  = j0 + ns*32 + ln;
        const int jc = j >> 3, off = j & 7;
        mh[(size_t)cc*P_SZ + iseg*256 + ((jc ^ (cc&31))*8 + off)] = (_Float16)acc[r];
    }
}

// ---------------- qf: Q2 += zz^T : M via mfma_f32_32x32x16_f16 --------------
// grid (8, 32): btile=256 (8 waves x 32 rows), i-group 8, LDS double-buffer.
// mh logical re-read = 8x8MB = 64 MB (L3-resident); 4.2M lane-atomics.
__global__ __launch_bounds__(512, 1) void qf_kernel(
        const float* __restrict__ z, const _Float16* __restrict__ mh,
        float* __restrict__ q2) {
    __shared__ __align__(16) char bt[2][64 * 512];
    const int tid = threadIdx.x;
    const int w = tid >> 6, lane = tid & 63;
    const int ln = lane & 31, half = lane >> 5;
    const int b0 = blockIdx.x * 256;
    const int ig = blockIdx.y;              // i-group of 8
    const int bb = b0 + w*32 + ln;          // A-operand m-row

    // zjh[ch] = f16(z[bb][ch*16 + half*8 .. +7]) packed, 64 VGPRs
    uint4 zjh[16];
    #pragma unroll
    for (int ch = 0; ch < 16; ++ch) {
        const floatx4* zp = (const floatx4*)(z + bb*D_SZ + ch*16 + half*8);
        floatx4 a = zp[0], b = zp[1];
        zjh[ch].x = pkrtz_u(a[0], a[1]);
        zjh[ch].y = pkrtz_u(a[2], a[3]);
        zjh[ch].z = pkrtz_u(b[0], b[1]);
        zjh[ch].w = pkrtz_u(b[2], b[3]);
    }
    float ziv[8];
    {
        const floatx4* zp = (const floatx4*)(z + bb*D_SZ + ig*8);
        floatx4 a = zp[0], b = zp[1];
        #pragma unroll
        for (int t = 0; t < 4; ++t) { ziv[t] = a[t]; ziv[4+t] = b[t]; }
    }

    floatx16 acc0, acc1;
    #pragma unroll
    for (int r = 0; r < 16; ++r) { acc0[r] = 0.f; acc1[r] = 0.f; }

    // stage i-slice into buffer sel: 2048 x 16B chunks over 512 threads
    #define STAGE(i, sel)                                                     \
        _Pragma("unroll")                                                     \
        for (int s = 0; s < 4; ++s) {                                         \
            const int e = s*512 + tid;                                        \
            gload16((const char*)mh +                                         \
                    ((size_t)(e >> 5)*P_SZ + (size_t)(i)*256)*2 + (e & 31)*16,\
                    bt[sel] + e*16);                                          \
        }

    STAGE(ig*8, 0);
    for (int il = 0; il < 8; ++il) {
        __syncthreads();                    // drains DMA for bt[il&1]
        if (il < 7) { STAGE(ig*8 + il + 1, (il + 1) & 1); }

        const float zi = ziv[il];
        const unsigned zu = pkrtz_u(zi, zi);
        H8U4 zb; zb.u.x = zu; zb.u.y = zu; zb.u.z = zu; zb.u.w = zu;
        const char* btc = bt[il & 1];
        #pragma unroll
        for (int ch = 0; ch < 16; ++ch) {
            H8U4 aj; aj.u = zjh[ch];
            h8 af = aj.h * zb.h;            // 4x v_pk_mul_f16
            const int pc = ((ch*2 + half) ^ ln) * 16;   // de-swizzle
            H8U4 f0, f1;
            f0.u = *(const uint4*)(btc + ln*512 + pc);
            f1.u = *(const uint4*)(btc + (32 + ln)*512 + pc);
            acc0 = __builtin_amdgcn_mfma_f32_32x32x16_f16(af, f0.h, acc0, 0, 0, 0);
            acc1 = __builtin_amdgcn_mfma_f32_32x32x16_f16(af, f1.h, acc1, 0, 0, 0);
        }
    }
    #undef STAGE

    // C/D: col=lane&31 (c), row=(r&3)+8*(r>>2)+4*half (b)  [m74/m101]
    #pragma unroll
    for (int r = 0; r < 16; ++r) {
        const int row  = (r&3) + 8*(r>>2) + 4*half;
        const int brow = b0 + w*32 + row;
        atomicAdd(q2 + brow*NC_SZ + ln,      acc0[r]);
        atomicAdd(q2 + brow*NC_SZ + 32 + ln, acc1[r]);
    }
}

// ---------------- final: qlin + dot/r2 + f64 score + softmax/argmax ---------
__global__ __launch_bounds__(256) void final_kernel(
        const float* __restrict__ z, const float* __restrict__ feat,
        const float* __restrict__ ws, float* __restrict__ out) {
    const int w = threadIdx.x >> 6, c = threadIdx.x & 63;
    const int b = blockIdx.x*4 + w;
    const float* __restrict__ zr  = z + b*D_SZ;
    const float* __restrict__ fr  = feat + b*F_SZ;
    const float* __restrict__ cqT = ws + WS_CQT;
    const float* __restrict__ wzT = ws + WS_WZT;
    const float* __restrict__ wfT = ws + WS_WFT;

    float qlin = ws[WS_BEFF + c];
    float dot = 0.f, r2 = 0.f;
    #pragma unroll 4
    for (int i = 0; i < D_SZ; ++i) {
        const float zi = zr[i];                 // wave-uniform -> scalar
        qlin = fmaf(zi, wzT[i*64 + c], qlin);   // coalesced
        dot  = fmaf(zi, cqT[i*64 + c], dot);
        r2   = fmaf(zi, zi, r2);
    }
    #pragma unroll 4
    for (int j = 0; j < F_SZ; ++j)
        qlin = fmaf(fr[j], wfT[j*64 + c], qlin);

    const float Q   = qlin + ws[WS_Q2 + b*64 + c];
    const float csq = ws[WS_CSQ + c];
    const float dsq = fmaf(-2.f, dot, r2) + csq;

    const double r2d = (double)r2, csqd = (double)csq, dsqd = (double)dsq;
    const double denom = (1.0 - r2d) * (1.0 - csqd);
    double arg = 1.0 + 2.0 * dsqd / (denom + 0.001);
    if (arg < 1.001) arg = 1.001;
    const double dist = acosh(arg);
    double tmp = 1.0 - r2d; if (tmp < 0.001) tmp = 0.001;
    double tau = 8.0 * tmp;  // sqrt(256)*0.5
    if (tau < 0.01) tau = 0.01;
    double r2c = r2d; if (r2c > 0.999) r2c = 0.999;
    const double lam = 2.0 / (1.0 - r2c + 0.001);
    const double score = -dist / tau + 0.1 * ((double)Q / lam) / tau;

    double m = score;
    #pragma unroll
    for (int off = 32; off > 0; off >>= 1) {
        double o = __shfl_xor(m, off, 64);
        m = fmax(m, o);
    }
    const double e = exp(score - m);
    double s = e;
    #pragma unroll
    for (int off = 32; off > 0; off >>= 1) s += __shfl_xor(s, off, 64);
    out[b*NC_SZ + c] = (float)(e / s);

    double bsc = score; int bix = c;
    #pragma unroll
    for (int off = 32; off > 0; off >>= 1) {
        double osc = __shfl_xor(bsc, off, 64);
        int    oix = __shfl_xor(bix, off, 64);
        if (osc > bsc || (osc == bsc && oix < bix)) { bsc = osc; bix = oix; }
    }
    if (c == 0) out[B_SZ*NC_SZ + b] = (float)bix;
}

extern "C" void kernel_launch(void* const* d_in, const int* in_sizes, int n_in,
                              void* d_out, int out_size, void* d_ws, size_t ws_size,
                              hipStream_t stream) {
    const float* z    = (const float*)d_in[0];
    const float* feat = (const float*)d_in[1];
    const float* Wqz  = (const float*)d_in[2];
    const float* bqz  = (const float*)d_in[3];
    const float* Wqf  = (const float*)d_in[4];
    const float* bqf  = (const float*)d_in[5];
    const float* gamma= (const float*)d_in[6];
    const float* cq   = (const float*)d_in[7];
    float* out = (float*)d_out;
    float* ws  = (float*)d_ws;
    _Float16* cqh = (_Float16*)(ws + WS_Q2);   // alias: dead after mc
    _Float16* mh  = (_Float16*)(ws + WS_MH);

    prep_kernel<<<201, 256, 0, stream>>>(Wqz, bqz, Wqf, bqf, cq, ws);
    mc_kernel<<<1024, 256, 0, stream>>>(gamma, cqh, mh);
    (void)hipMemsetAsync(ws + WS_Q2, 0, (size_t)B_SZ*NC_SZ*sizeof(float), stream);
    qf_kernel<<<dim3(8, 32), 512, 0, stream>>>(z, mh, ws + WS_Q2);
    final_kernel<<<512, 256, 0, stream>>>(z, feat, ws, out);
}

// Round 7
// 202.596 us; speedup vs baseline: 1.4197x; 1.2916x over previous
//
#include <hip/hip_runtime.h>
#include <hip/hip_bf16.h>
#include <hip/hip_fp16.h>

// B=2048, D=256, K=256, NC=64, F=512.
// Q[b,c] = Qlin[b,c] + z^T M_c z, M_c = sum_k cq[c,k] Gamma_k.
// R7 = R6 + Dekker-compensated f16 MFMA for the precision-critical linear
// terms (feat·wf, z·cq): x = x_hi + x_lo/1024, dot = hh + (lh + hl)/1024.
// Restores the f32-level score accuracy that R5's argmax relied on.

#define B_SZ 2048
#define D_SZ 256
#define K_SZ 256
#define NC_SZ 64
#define F_SZ 512
#define P_SZ 65536

typedef float  floatx4  __attribute__((ext_vector_type(4)));
typedef float  floatx16 __attribute__((ext_vector_type(16)));
typedef _Float16 h8 __attribute__((ext_vector_type(8)));
typedef __fp16  fp16x2 __attribute__((ext_vector_type(2)));
union H8U4 { uint4 u; h8 h; };

// ws layout (f32 offsets).
// cqh ALIASES Q2 head (dead after mc; memset follows mc).
// dot ALIASES MH head (mh dead after qf; lin2's s=3 plain-stores after qf).
#define WS_WZT   0        // 256*64 f32 (dead after prep2)
#define WS_WFT   16384    // 512*64 f32 (dead after prep2)
#define WS_BEFF  49152    // 64
#define WS_CSQ   49216    // 64
#define WS_CQT   49280    // 256*64 f32 (dead after prep2)
#define WS_Q2    65664    // 2048*64 f32 accum (also cqh f16[64*256] pre-memset)
#define WS_MH    196736   // f16[64*65536] (qf input; head reused as dot f32[2048*64])
#define WS_WALL  2293888  // 7 x 32KB pre-swizzled f16 LDS images = 224 KB
// end: 2351232 f32 = 9.40 MB

__device__ __forceinline__ unsigned pkrtz_u(float a, float b) {
    fp16x2 r = __builtin_amdgcn_cvt_pkrtz(a, b);
    return __builtin_bit_cast(unsigned, r);
}
__device__ __forceinline__ unsigned packh2(_Float16 a, _Float16 b) {
    union { _Float16 h[2]; unsigned u; } r; r.h[0] = a; r.h[1] = b; return r.u;
}
__device__ __forceinline__ unsigned packh(float a, float b) {
    return packh2((_Float16)a, (_Float16)b);
}

__device__ __forceinline__ void gload16(const void* g, void* l) {
    __builtin_amdgcn_global_load_lds(
        (const __attribute__((address_space(1))) unsigned*)g,
        (__attribute__((address_space(3))) unsigned*)l, 16, 0, 0);
}

// ---------------- prep: collapsed weights (f32), cqT, cqh, beff, csq --------
__global__ __launch_bounds__(256) void prep_kernel(
        const float* __restrict__ Wqz, const float* __restrict__ bqz,
        const float* __restrict__ Wqf, const float* __restrict__ bqf,
        const float* __restrict__ cq,  float* __restrict__ ws) {
    const int tid = threadIdx.x;
    const int w = tid >> 6, c = tid & 63;
    const int bid = blockIdx.x;

    if (bid >= 193) {  // cqh convert: no barrier on this path
        _Float16* cqh = (_Float16*)(ws + WS_Q2);
        const int idx = (bid - 193)*256 + tid;   // 0..2047, 8 f16 each
        const floatx4* sp = (const floatx4*)(cq + idx*8);
        floatx4 a = sp[0], b = sp[1];
        uint4 u = { pkrtz_u(a[0],a[1]), pkrtz_u(a[2],a[3]),
                    pkrtz_u(b[0],b[1]), pkrtz_u(b[2],b[3]) };
        *(uint4*)(cqh + idx*8) = u;
        return;
    }

    __shared__ float cqL[64*257];
    #pragma unroll
    for (int s = 0; s < 16; ++s) {
        const int e4 = s*256 + tid;
        const int row = e4 >> 6, col = (e4 & 63)*4;
        floatx4 v = *(const floatx4*)(cq + e4*4);
        #pragma unroll
        for (int u = 0; u < 4; ++u) cqL[row*257 + col + u] = v[u];
    }
    __syncthreads();

    if (bid < 64) {
        const int i = bid*4 + w;
        float acc = 0.f;
        #pragma unroll 4
        for (int k = 0; k < K_SZ; ++k)
            acc = fmaf(cqL[c*257 + k], Wqz[k*D_SZ + i], acc);
        ws[WS_WZT + i*64 + c] = acc;
        ws[WS_CQT + i*64 + c] = cqL[c*257 + i];
    } else if (bid < 192) {
        const int j = (bid - 64)*4 + w;
        float acc = 0.f;
        #pragma unroll 4
        for (int k = 0; k < K_SZ; ++k)
            acc = fmaf(cqL[c*257 + k], Wqf[k*F_SZ + j], acc);
        ws[WS_WFT + j*64 + c] = acc;
    } else {
        if (w == 0) {
            float acc = 0.f;
            for (int k = 0; k < K_SZ; ++k)
                acc = fmaf(cqL[c*257 + k], bqz[k] + bqf[k], acc);
            ws[WS_BEFF + c] = acc;
        } else if (w == 1) {
            float acc = 0.f;
            for (int i = 0; i < D_SZ; ++i) {
                const float v = cqL[c*257 + i];
                acc = fmaf(v, v, acc);
            }
            ws[WS_CSQ + c] = acc;
        }
    }
}

// ---------------- prep2: pack 7 wAll images (pre-swizzled) ------------------
// slices: 0=wz_hi | 1=wf0_hi 2=wf0_lo | 3=wf1_hi 4=wf1_lo | 5=cq_hi 6=cq_lo
// lo images store (v - f16(v))*1024. Image layout matches lin2's LDS reads.
__global__ __launch_bounds__(256) void prep2_kernel(float* __restrict__ ws) {
    const int gi = blockIdx.x*256 + threadIdx.x;   // 0..14335
    const int s  = gi >> 11, e = gi & 2047;
    const int cr = e >> 5,  u = e & 31;
    const float* __restrict__ src =
        (s == 0) ? ws + WS_WZT :
        (s <= 2) ? ws + WS_WFT :
        (s <= 4) ? ws + WS_WFT + 16384 : ws + WS_CQT;
    const bool lo = (s == 2) || (s == 4) || (s == 6);
    float v[8];
    #pragma unroll
    for (int off = 0; off < 8; ++off)
        v[off] = src[(u*8 + off)*64 + cr];
    uint4 o;
    if (!lo) {
        o.x = packh(v[0], v[1]); o.y = packh(v[2], v[3]);
        o.z = packh(v[4], v[5]); o.w = packh(v[6], v[7]);
    } else {
        float l[8];
        #pragma unroll
        for (int off = 0; off < 8; ++off) {
            const _Float16 h = (_Float16)v[off];
            l[off] = (v[off] - (float)h) * 1024.f;
        }
        o.x = pkrtz_u(l[0], l[1]); o.y = pkrtz_u(l[2], l[3]);
        o.z = pkrtz_u(l[4], l[5]); o.w = pkrtz_u(l[6], l[7]);
    }
    char* wall = (char*)(ws + WS_WALL);
    *(uint4*)(wall + s*32768 + cr*512 + ((u ^ (cr & 31)) << 4)) = o;
}

// ---------------- mc: M[c,p] = sum_k cq[c,k] Gamma[k,p] via MFMA, no LDS ----
__global__ __launch_bounds__(256, 4) void mc_kernel(
        const float* __restrict__ gamma, const _Float16* __restrict__ cqh,
        _Float16* __restrict__ mh) {
    const int tid = threadIdx.x;
    const int w = tid >> 6, lane = tid & 63;
    const int ln = lane & 31, half = lane >> 5;
    const int mt = w >> 1, ns = w & 1;
    const int p0 = blockIdx.x * 64;
    const int iseg = p0 >> 8, j0 = p0 & 255;

    floatx16 acc;
    #pragma unroll
    for (int r = 0; r < 16; ++r) acc[r] = 0.f;

    const int arow = mt*32 + ln;
    const float* __restrict__ gbase = gamma + (size_t)(half*8)*P_SZ + p0 + ns*32 + ln;

    #pragma unroll 2
    for (int kc = 0; kc < 16; ++kc) {
        float g[8];
        #pragma unroll
        for (int kk = 0; kk < 8; ++kk)
            g[kk] = gbase[(size_t)(kc*16 + kk)*P_SZ];     // coalesced 128B/row
        H8U4 a; a.u = *(const uint4*)(cqh + arow*256 + kc*16 + half*8);
        H8U4 b;
        b.u.x = pkrtz_u(g[0], g[1]);
        b.u.y = pkrtz_u(g[2], g[3]);
        b.u.z = pkrtz_u(g[4], g[5]);
        b.u.w = pkrtz_u(g[6], g[7]);
        acc = __builtin_amdgcn_mfma_f32_32x32x16_f16(a.h, b.h, acc, 0, 0, 0);
    }
    // D: col=lane&31 (p), row=(r&3)+8*(r>>2)+4*half (c)  [m74/m101]
    #pragma unroll
    for (int r = 0; r < 16; ++r) {
        const int cc = mt*32 + (r&3) + 8*(r>>2) + 4*half;
        const int j  = j0 + ns*32 + ln;
        const int jc = j >> 3, off = j & 7;
        mh[(size_t)cc*P_SZ + iseg*256 + ((jc ^ (cc&31))*8 + off)] = (_Float16)acc[r];
    }
}

// ---------------- qf: Q2 += zz^T : M via mfma_f32_32x32x16_f16 --------------
// grid (8, 32): btile=256 (8 waves x 32 rows), i-group 8, LDS double-buffer.
__global__ __launch_bounds__(512, 1) void qf_kernel(
        const float* __restrict__ z, const _Float16* __restrict__ mh,
        float* __restrict__ q2) {
    __shared__ __align__(16) char bt[2][64 * 512];
    const int tid = threadIdx.x;
    const int w = tid >> 6, lane = tid & 63;
    const int ln = lane & 31, half = lane >> 5;
    const int b0 = blockIdx.x * 256;
    const int ig = blockIdx.y;
    const int bb = b0 + w*32 + ln;

    uint4 zjh[16];
    #pragma unroll
    for (int ch = 0; ch < 16; ++ch) {
        const floatx4* zp = (const floatx4*)(z + bb*D_SZ + ch*16 + half*8);
        floatx4 a = zp[0], b = zp[1];
        zjh[ch].x = pkrtz_u(a[0], a[1]);
        zjh[ch].y = pkrtz_u(a[2], a[3]);
        zjh[ch].z = pkrtz_u(b[0], b[1]);
        zjh[ch].w = pkrtz_u(b[2], b[3]);
    }
    float ziv[8];
    {
        const floatx4* zp = (const floatx4*)(z + bb*D_SZ + ig*8);
        floatx4 a = zp[0], b = zp[1];
        #pragma unroll
        for (int t = 0; t < 4; ++t) { ziv[t] = a[t]; ziv[4+t] = b[t]; }
    }

    floatx16 acc0, acc1;
    #pragma unroll
    for (int r = 0; r < 16; ++r) { acc0[r] = 0.f; acc1[r] = 0.f; }

    #define STAGE(i, sel)                                                     \
        _Pragma("unroll")                                                     \
        for (int s = 0; s < 4; ++s) {                                         \
            const int e = s*512 + tid;                                        \
            gload16((const char*)mh +                                         \
                    ((size_t)(e >> 5)*P_SZ + (size_t)(i)*256)*2 + (e & 31)*16,\
                    bt[sel] + e*16);                                          \
        }

    STAGE(ig*8, 0);
    for (int il = 0; il < 8; ++il) {
        __syncthreads();
        if (il < 7) { STAGE(ig*8 + il + 1, (il + 1) & 1); }

        const float zi = ziv[il];
        const unsigned zu = pkrtz_u(zi, zi);
        H8U4 zb; zb.u.x = zu; zb.u.y = zu; zb.u.z = zu; zb.u.w = zu;
        const char* btc = bt[il & 1];
        #pragma unroll
        for (int ch = 0; ch < 16; ++ch) {
            H8U4 aj; aj.u = zjh[ch];
            h8 af = aj.h * zb.h;
            const int pc = ((ch*2 + half) ^ ln) * 16;
            H8U4 f0, f1;
            f0.u = *(const uint4*)(btc + ln*512 + pc);
            f1.u = *(const uint4*)(btc + (32 + ln)*512 + pc);
            acc0 = __builtin_amdgcn_mfma_f32_32x32x16_f16(af, f0.h, acc0, 0, 0, 0);
            acc1 = __builtin_amdgcn_mfma_f32_32x32x16_f16(af, f1.h, acc1, 0, 0, 0);
        }
    }
    #undef STAGE

    #pragma unroll
    for (int r = 0; r < 16; ++r) {
        const int row  = (r&3) + 8*(r>>2) + 4*half;
        const int brow = b0 + w*32 + row;
        atomicAdd(q2 + brow*NC_SZ + ln,      acc0[r]);
        atomicAdd(q2 + brow*NC_SZ + 32 + ln, acc1[r]);
    }
}

// ---------------- lin2: compensated f16 MFMA linear terms -------------------
// grid (16, 4): btile=128. s=0: z·wz (plain, error negligible) -> q2.
// s=1: feat[0:256]·wf0, s=2: feat[256:512]·wf1 (Dekker) -> q2.
// s=3: z·cq (Dekker) -> dot (plain store).
__global__ __launch_bounds__(256) void lin2_kernel(
        const float* __restrict__ z, const float* __restrict__ feat,
        const float* __restrict__ wall_f, float* __restrict__ q2,
        float* __restrict__ dot) {
    __shared__ __align__(16) char bt[2][64 * 512];
    const char* wall = (const char*)wall_f;
    const int tid = threadIdx.x;
    const int w = tid >> 6, lane = tid & 63;
    const int ln = lane & 31, half = lane >> 5;
    const int b0 = blockIdx.x * 128;
    const int s  = blockIdx.y;
    const int bb = b0 + w*32 + ln;
    const int s_hi = (s == 0) ? 0 : (s == 1) ? 1 : (s == 2) ? 3 : 5;

    #pragma unroll
    for (int e0 = 0; e0 < 8; ++e0) {
        const int e = e0*256 + tid;
        gload16(wall + s_hi*32768 + e*16, bt[0] + e*16);
    }
    if (s > 0) {
        #pragma unroll
        for (int e0 = 0; e0 < 8; ++e0) {
            const int e = e0*256 + tid;
            gload16(wall + (s_hi + 1)*32768 + e*16, bt[1] + e*16);
        }
    }
    const float* __restrict__ arow =
        (s == 0 || s == 3) ? z + bb*D_SZ : feat + bb*F_SZ + (s == 2 ? 256 : 0);
    __syncthreads();

    floatx16 hh0, hh1, lh0, lh1, hl0, hl1;
    #pragma unroll
    for (int r = 0; r < 16; ++r) {
        hh0[r] = 0.f; hh1[r] = 0.f; lh0[r] = 0.f;
        lh1[r] = 0.f; hl0[r] = 0.f; hl1[r] = 0.f;
    }

    #pragma unroll
    for (int ch = 0; ch < 16; ++ch) {
        const floatx4* ap = (const floatx4*)(arow + ch*16 + half*8);
        floatx4 a4 = ap[0], b4 = ap[1];
        float vv[8];
        #pragma unroll
        for (int t = 0; t < 4; ++t) { vv[t] = a4[t]; vv[4+t] = b4[t]; }
        _Float16 hc[8];
        #pragma unroll
        for (int j = 0; j < 8; ++j) hc[j] = (_Float16)vv[j];
        H8U4 ah;
        ah.u.x = packh2(hc[0], hc[1]); ah.u.y = packh2(hc[2], hc[3]);
        ah.u.z = packh2(hc[4], hc[5]); ah.u.w = packh2(hc[6], hc[7]);

        const int pc = ((ch*2 + half) ^ ln) * 16;
        H8U4 f0, f1;
        f0.u = *(const uint4*)(bt[0] + ln*512 + pc);
        f1.u = *(const uint4*)(bt[0] + (32 + ln)*512 + pc);
        hh0 = __builtin_amdgcn_mfma_f32_32x32x16_f16(ah.h, f0.h, hh0, 0, 0, 0);
        hh1 = __builtin_amdgcn_mfma_f32_32x32x16_f16(ah.h, f1.h, hh1, 0, 0, 0);

        if (s > 0) {
            float l[8];
            #pragma unroll
            for (int j = 0; j < 8; ++j) l[j] = (vv[j] - (float)hc[j]) * 1024.f;
            H8U4 al;
            al.u.x = pkrtz_u(l[0], l[1]); al.u.y = pkrtz_u(l[2], l[3]);
            al.u.z = pkrtz_u(l[4], l[5]); al.u.w = pkrtz_u(l[6], l[7]);
            H8U4 g0, g1;
            g0.u = *(const uint4*)(bt[1] + ln*512 + pc);
            g1.u = *(const uint4*)(bt[1] + (32 + ln)*512 + pc);
            lh0 = __builtin_amdgcn_mfma_f32_32x32x16_f16(al.h, f0.h, lh0, 0, 0, 0);
            lh1 = __builtin_amdgcn_mfma_f32_32x32x16_f16(al.h, f1.h, lh1, 0, 0, 0);
            hl0 = __builtin_amdgcn_mfma_f32_32x32x16_f16(ah.h, g0.h, hl0, 0, 0, 0);
            hl1 = __builtin_amdgcn_mfma_f32_32x32x16_f16(ah.h, g1.h, hl1, 0, 0, 0);
        }
    }

    const float is = 1.0f / 1024.0f;
    #pragma unroll
    for (int r = 0; r < 16; ++r) {
        const int row  = (r&3) + 8*(r>>2) + 4*half;
        const int brow = b0 + w*32 + row;
        float v0 = hh0[r], v1 = hh1[r];
        if (s > 0) { v0 += (lh0[r] + hl0[r])*is; v1 += (lh1[r] + hl1[r])*is; }
        if (s < 3) {
            atomicAdd(q2 + brow*NC_SZ + ln,      v0);
            atomicAdd(q2 + brow*NC_SZ + 32 + ln, v1);
        } else {
            dot[brow*NC_SZ + ln]      = v0;
            dot[brow*NC_SZ + 32 + ln] = v1;
        }
    }
}

// ---------------- final: r2 reduce + f64 score + softmax/argmax -------------
__global__ __launch_bounds__(256) void final_kernel(
        const float* __restrict__ z, const float* __restrict__ ws,
        const float* __restrict__ dot, float* __restrict__ out) {
    const int w = threadIdx.x >> 6, c = threadIdx.x & 63;
    const int b = blockIdx.x*4 + w;

    // r2 = |z_b|^2 : lane c owns 4 elements, butterfly reduce
    const floatx4 zv = *(const floatx4*)(z + b*D_SZ + c*4);
    float r2 = zv[0]*zv[0] + zv[1]*zv[1] + zv[2]*zv[2] + zv[3]*zv[3];
    #pragma unroll
    for (int off = 32; off > 0; off >>= 1)
        r2 += __shfl_xor(r2, off, 64);

    const float Q   = ws[WS_Q2 + b*64 + c] + ws[WS_BEFF + c];
    const float csq = ws[WS_CSQ + c];
    const float dsq = fmaf(-2.f, dot[b*64 + c], r2) + csq;

    const double r2d = (double)r2, csqd = (double)csq, dsqd = (double)dsq;
    const double denom = (1.0 - r2d) * (1.0 - csqd);
    double arg = 1.0 + 2.0 * dsqd / (denom + 0.001);
    if (arg < 1.001) arg = 1.001;
    const double dist = acosh(arg);
    double tmp = 1.0 - r2d; if (tmp < 0.001) tmp = 0.001;
    double tau = 8.0 * tmp;  // sqrt(256)*0.5
    if (tau < 0.01) tau = 0.01;
    double r2c = r2d; if (r2c > 0.999) r2c = 0.999;
    const double lam = 2.0 / (1.0 - r2c + 0.001);
    const double score = -dist / tau + 0.1 * ((double)Q / lam) / tau;

    double m = score;
    #pragma unroll
    for (int off = 32; off > 0; off >>= 1) {
        double o = __shfl_xor(m, off, 64);
        m = fmax(m, o);
    }
    const double e = exp(score - m);
    double s = e;
    #pragma unroll
    for (int off = 32; off > 0; off >>= 1) s += __shfl_xor(s, off, 64);
    out[b*NC_SZ + c] = (float)(e / s);

    double bsc = score; int bix = c;
    #pragma unroll
    for (int off = 32; off > 0; off >>= 1) {
        double osc = __shfl_xor(bsc, off, 64);
        int    oix = __shfl_xor(bix, off, 64);
        if (osc > bsc || (osc == bsc && oix < bix)) { bsc = osc; bix = oix; }
    }
    if (c == 0) out[B_SZ*NC_SZ + b] = (float)bix;
}

extern "C" void kernel_launch(void* const* d_in, const int* in_sizes, int n_in,
                              void* d_out, int out_size, void* d_ws, size_t ws_size,
                              hipStream_t stream) {
    const float* z    = (const float*)d_in[0];
    const float* feat = (const float*)d_in[1];
    const float* Wqz  = (const float*)d_in[2];
    const float* bqz  = (const float*)d_in[3];
    const float* Wqf  = (const float*)d_in[4];
    const float* bqf  = (const float*)d_in[5];
    const float* gamma= (const float*)d_in[6];
    const float* cq   = (const float*)d_in[7];
    float* out = (float*)d_out;
    float* ws  = (float*)d_ws;
    _Float16* cqh = (_Float16*)(ws + WS_Q2);   // alias: dead after mc
    _Float16* mh  = (_Float16*)(ws + WS_MH);
    float*    dot = ws + WS_MH;                // alias: mh dead after qf

    prep_kernel<<<201, 256, 0, stream>>>(Wqz, bqz, Wqf, bqf, cq, ws);
    prep2_kernel<<<56, 256, 0, stream>>>(ws);
    mc_kernel<<<1024, 256, 0, stream>>>(gamma, cqh, mh);
    (void)hipMemsetAsync(ws + WS_Q2, 0, (size_t)B_SZ*NC_SZ*sizeof(float), stream);
    qf_kernel<<<dim3(8, 32), 512, 0, stream>>>(z, mh, ws + WS_Q2);
    lin2_kernel<<<dim3(16, 4), 256, 0, stream>>>(z, feat, ws + WS_WALL,
                                                 ws + WS_Q2, dot);
    final_kernel<<<512, 256, 0, stream>>>(z, ws, dot, out);
}